// Round 8
// baseline (2677.823 us; speedup 1.0000x reference)
//
#include <hip/hip_runtime.h>

// EagerRNN: B=64, T=512, F=512, H=1024.
// xproj = x @ W[:512] + b  (32768x1024x512 GEMM)
// scan:  state = tanh(xproj[:,t,:] + state @ W[512:])   512 sequential steps
// out: final state (64,1024) f32.
//
// Phase 2: persistent 32-block kernel. Each block owns one 64-col N-slice of
// TWO independent batch-groups (gA=pair*2, gB=pair*2+1) and ping-pongs:
// while group X's tagged stores propagate through the fabric, the block
// computes group Y's step (r3's overlap idea), using r7's PROVEN drain-free
// self-validating exchange (stolen LSB tag = (s>>1)&1 per aligned 8B word;
// no vmcnt drain, no flags -> r3's pipeline-coupling bug is impossible).
// Register catastrophe of r3 fixed by construction: Wh = 12 kk in regs
// (48 VGPR) + 20 kk in LDS (80KB); stA+stB 64KB; total LDS ~146KB, 1 blk/CU.
// Serial tail shortened: 3-op exp/rcp tanh instead of libm tanhf.
//
// Overwrite/deadlock safety (same induction as r7, per pair of groups):
// a block stores X(t+1) only after validating ALL of X(t), which certifies
// every block finished its global reads of X(t-1); slot content is bounded
// to {s-2, s} which the 1-bit tag distinguishes. k_init pre-tags parity-1
// with 1 so init zeros cannot falsely validate as state 1 (r6 lesson).

typedef _Float16 f16;
typedef _Float16 f16x8 __attribute__((ext_vector_type(8)));
typedef _Float16 f16x4 __attribute__((ext_vector_type(4)));
typedef float f32x4 __attribute__((ext_vector_type(4)));
typedef unsigned long long u64;
typedef unsigned u32;

#define B_  64
#define T_  512
#define F_  512
#define H_  1024

// workspace layout (bytes)
#define XPH_OFF  0ull                         // f16 [T][B][H]  = 64 MB
#define WXT_OFF  67108864ull                  // f16 [H][F]     = 1 MB
#define WHT_OFF  68157440ull                  // f16 [H][H]     = 2 MB
#define SBUF_OFF 70254592ull                  // f16 image, 2 parities x 4 groups x 32768 B
#define WS_NEED  70516736ull

#define ALD64(p)    __hip_atomic_load((const u64*)(p), __ATOMIC_RELAXED, __HIP_MEMORY_SCOPE_AGENT)
#define AST64(p, v) __hip_atomic_store((u64*)(p), (v), __ATOMIC_RELAXED, __HIP_MEMORY_SCOPE_AGENT)

// 3-op tanh: e = 2^(2x*log2e) = e^{2x}; tanh = 1 - 2/(e+1). Saturates
// correctly at +-1 for large |x|; error ~1e-6 << f16 quantization.
__device__ __forceinline__ float fast_tanh(float x) {
  float e;
  asm("v_exp_f32 %0, %1" : "=v"(e) : "v"(x * 2.885390081777927f));
  float r;
  asm("v_rcp_f32 %0, %1" : "=v"(r) : "v"(e + 1.0f));
  return 1.0f - 2.0f * r;
}

// ---------------------------------------------------------------------------
// init: parity-0 image words = 0 (state0 = 0, tag 0), parity-1 words = 1
// (tag 1 -> cannot falsely validate at t=1, where want = 0).
__global__ __launch_bounds__(256) void k_init(u64* __restrict__ sbuf) {
  const unsigned i = blockIdx.x * 256 + threadIdx.x;   // 0..32767
  sbuf[i] = (i >= 16384) ? 1ull : 0ull;                // 16384 u64 per parity
}

// ---------------------------------------------------------------------------
// prep: W f32 [1536][1024] -> WxT f16 [h][k<512], WhT f16 [h][k<1024]
__global__ __launch_bounds__(256) void k_prep(const float* __restrict__ W,
                                              f16* __restrict__ WxT,
                                              f16* __restrict__ WhT) {
  __shared__ float tile[32][33];
  const int tid = threadIdx.x;
  const int kt = blockIdx.x >> 5;   // 0..47 (32 k-rows each)
  const int ht = blockIdx.x & 31;   // 0..31 (32 h-cols each)
#pragma unroll
  for (int p = 0; p < 4; ++p) {
    int kr = p * 8 + (tid >> 5);
    tile[kr][tid & 31] = W[(size_t)(kt * 32 + kr) * 1024 + ht * 32 + (tid & 31)];
  }
  __syncthreads();
  const int hl = tid >> 3;   // 0..31
  const int kq = tid & 7;    // 0..7  -> 4 k each
  f16x4 v;
#pragma unroll
  for (int j = 0; j < 4; ++j) v[j] = (f16)tile[kq * 4 + j][hl];
  const int h = ht * 32 + hl;
  const int kg = kt * 32 + kq * 4;
  if (kg < 512) *(f16x4*)(WxT + (size_t)h * 512 + kg) = v;
  else          *(f16x4*)(WhT + (size_t)h * 1024 + (kg - 512)) = v;
}

// ---------------------------------------------------------------------------
// phase 1: xph[t*64+b][h] = f16( x[b][t][:] @ Wx[:][h] + bias[h] )
__global__ __launch_bounds__(256) void k_xproj(const float* __restrict__ x,
                                               const f16* __restrict__ WxT,
                                               const float* __restrict__ bias,
                                               f16* __restrict__ xph) {
  __shared__ __align__(16) unsigned char Al[65536];  // [64 m][512 k] f16, swizzled
  __shared__ __align__(16) unsigned char Bl[65536];  // [64 n][512 k] f16, swizzled
  const int tid = threadIdx.x;
  const int l = tid & 63, w = tid >> 6;
  const int lane15 = l & 15, sub = l >> 4;
  const int m0 = blockIdx.x * 64;
  const int bidx = m0 >> 9;     // batch
  const int t0 = m0 & 511;      // time base

  {
    const int r = tid >> 2, qq = tid & 3;
    const float* xs = x + (size_t)(m0 + r) * 512;
#pragma unroll
    for (int i = 0; i < 16; ++i) {
      int s = qq * 16 + i;          // 16B slot 0..63
      int c = s ^ (r & 7);          // source k-chunk (swizzle on source)
      const float4 f0 = *(const float4*)(xs + c * 8);
      const float4 f1 = *(const float4*)(xs + c * 8 + 4);
      f16x8 v;
      v[0] = (f16)f0.x; v[1] = (f16)f0.y; v[2] = (f16)f0.z; v[3] = (f16)f0.w;
      v[4] = (f16)f1.x; v[5] = (f16)f1.y; v[6] = (f16)f1.z; v[7] = (f16)f1.w;
      *(f16x8*)(Al + r * 1024 + s * 16) = v;
    }
  }

  const int mh = (w >> 1) * 32, nh = (w & 1) * 32;
  const int rA0 = mh + lane15, rA1 = mh + 16 + lane15;
  const int rB0 = nh + lane15, rB1 = nh + 16 + lane15;

  for (int nb = 0; nb < 16; ++nb) {
    const int n0 = nb * 64;
    __syncthreads();   // Bl safe to overwrite
    {
      const int r = tid >> 2, qq = tid & 3;
      const f16* bs = WxT + (size_t)(n0 + r) * 512;
#pragma unroll
      for (int i = 0; i < 16; ++i) {
        int s = qq * 16 + i;
        int c = s ^ (r & 7);
        f16x8 v = *(const f16x8*)(bs + c * 8);
        *(f16x8*)(Bl + r * 1024 + s * 16) = v;
      }
    }
    __syncthreads();
    f32x4 acc00 = {0.f,0.f,0.f,0.f}, acc01 = {0.f,0.f,0.f,0.f};
    f32x4 acc10 = {0.f,0.f,0.f,0.f}, acc11 = {0.f,0.f,0.f,0.f};
#pragma unroll
    for (int kk = 0; kk < 16; ++kk) {
      const int s = kk * 4 + sub;
      f16x8 a0 = *(const f16x8*)(Al + rA0 * 1024 + ((s ^ (rA0 & 7)) << 4));
      f16x8 a1 = *(const f16x8*)(Al + rA1 * 1024 + ((s ^ (rA1 & 7)) << 4));
      f16x8 b0 = *(const f16x8*)(Bl + rB0 * 1024 + ((s ^ (rB0 & 7)) << 4));
      f16x8 b1 = *(const f16x8*)(Bl + rB1 * 1024 + ((s ^ (rB1 & 7)) << 4));
      acc00 = __builtin_amdgcn_mfma_f32_16x16x32_f16(a0, b0, acc00, 0, 0, 0);
      acc01 = __builtin_amdgcn_mfma_f32_16x16x32_f16(a0, b1, acc01, 0, 0, 0);
      acc10 = __builtin_amdgcn_mfma_f32_16x16x32_f16(a1, b0, acc10, 0, 0, 0);
      acc11 = __builtin_amdgcn_mfma_f32_16x16x32_f16(a1, b1, acc11, 0, 0, 0);
    }
    const float bv0 = bias[n0 + nh + lane15];
    const float bv1 = bias[n0 + nh + 16 + lane15];
#pragma unroll
    for (int j = 0; j < 4; ++j) {
      const int r0 = mh + sub * 4 + j;
      const int r1 = mh + 16 + sub * 4 + j;
      const size_t row0 = (size_t)(t0 + r0) * 64 + bidx;
      const size_t row1 = (size_t)(t0 + r1) * 64 + bidx;
      xph[row0 * 1024 + n0 + nh + lane15]      = (f16)(acc00[j] + bv0);
      xph[row0 * 1024 + n0 + nh + 16 + lane15] = (f16)(acc01[j] + bv1);
      xph[row1 * 1024 + n0 + nh + lane15]      = (f16)(acc10[j] + bv0);
      xph[row1 * 1024 + n0 + nh + 16 + lane15] = (f16)(acc11[j] + bv1);
    }
  }
}

// ---------------------------------------------------------------------------
// phase 2: persistent recurrence, 2 groups per block, tag-exchange pipelined.
// 32 blocks = 2 pairs x 16 slices. LDS: WhL 80KB (kk 12..31) + stA 32KB +
// stB 32KB + tbuf 2.2KB = ~146KB.
__global__ __launch_bounds__(256, 1) void k_rnn(const f16* __restrict__ xph,
                                                const f16* __restrict__ WhT,
                                                f16* sbuf,
                                                float* __restrict__ out) {
  __shared__ __align__(16) unsigned char lds[149632];
  unsigned char* WhL  = lds;             // 64 rows x 1280 B (kslot 48..127)
  unsigned char* stA  = lds + 81920;     // 16 rows x 2048 B (swizzled)
  unsigned char* stB  = lds + 114688;    // 16 rows x 2048 B
  unsigned char* tbuf = lds + 147456;    // 16 rows x 136 B (wave transpose)
  const int tid = threadIdx.x;
  const int l = tid & 63, w = tid >> 6;
  const int lane15 = l & 15, sub = l >> 4;
  const int bid = blockIdx.x;
  const int pair = bid & 1, slice = bid >> 1;     // slice 0..15
  const int gA = pair * 2, gB = pair * 2 + 1;

  // Wh slice -> LDS, kslot 48..127 (kk 12..31), swizzled 16B slots
  for (int i = 0; i < 20; ++i) {
    int s = i * 256 + tid;          // 0..5119
    int r = s / 80;
    int ks = 48 + (s - r * 80);     // kslot 48..127
    f16x8 v = *(const f16x8*)(WhT + (size_t)(slice * 64 + r) * 1024 + ks * 8);
    *(f16x8*)(WhL + r * 1280 + ((ks ^ (r & 7)) - 48) * 16) = v;
  }
  // kk = 0..11 B-fragments in registers (stationary all 512 steps)
  const int colL = slice * 64 + w * 16 + lane15;
  f16x8 breg[12];
  {
    const f16* src = WhT + (size_t)colL * 1024 + sub * 8;
#pragma unroll
    for (int kk = 0; kk < 12; ++kk) breg[kk] = *(const f16x8*)(src + kk * 32);
  }
#pragma unroll
  for (int kk = 0; kk < 12; ++kk) asm volatile("" : "+v"(breg[kk]));

  const int rA = lane15, xA = rA & 7;
  const int rB = w * 16 + lane15, xB = rB & 7;
  const unsigned char* whb = WhL + rB * 1280;
  const unsigned char* stAb = stA + rA * 2048;
  const unsigned char* stBb = stB + rA * 2048;

  const int p = tid >> 4, q = tid & 15;
  const int c0s = slice * 64 + w * 16 + sub * 4;
  const int stoff = lane15 * 2048 + (((c0s >> 3) ^ (lane15 & 7)) << 4) + (c0s & 7) * 2;
  const size_t baseA = (size_t)gA * 32768, baseB = (size_t)gB * 32768;

  // prologue: stA = state0 = 0; xpvA(0)
#pragma unroll
  for (int i = 0; i < 16; ++i) *(u64*)(stA + i * 2048 + tid * 8) = 0ull;
  float xpvA[4], xpvB[4];
#pragma unroll
  for (int j = 0; j < 4; ++j)
    xpvA[j] = (float)xph[(size_t)(gA * 16 + sub * 4 + j) * 1024 + colL];
  __syncthreads();

  for (int t = 0; t < T_; ++t) {
    // ================= phase A: group gA, step t -> t+1 ====================
    {
      // issue staging loads for B(t) (fire; validated after MFMA)
      u64 tmp[16];
      const char* src = (const char*)sbuf + (size_t)(t & 1) * 131072 + baseB + p * 128 + q * 8;
#pragma unroll
      for (int i = 0; i < 16; ++i) tmp[i] = ALD64(src + i * 2048);
      // prefetch xpvB(t) (HBM latency hides under MFMA)
#pragma unroll
      for (int j = 0; j < 4; ++j)
        xpvB[j] = (float)xph[(size_t)(t * 64 + gB * 16 + sub * 4 + j) * 1024 + colL];

      f32x4 acc0 = {0.f,0.f,0.f,0.f}, acc1 = {0.f,0.f,0.f,0.f};
#pragma unroll
      for (int kk = 0; kk < 32; ++kk) {
        const int s = kk * 4 + sub;
        f16x8 a = *(const f16x8*)(stAb + ((s ^ xA) << 4));
        f16x8 b = (kk < 12) ? breg[kk]
                            : *(const f16x8*)(whb + (((s ^ xB) - 48) << 4));
        if (kk & 1) acc1 = __builtin_amdgcn_mfma_f32_16x16x32_f16(a, b, acc1, 0, 0, 0);
        else        acc0 = __builtin_amdgcn_mfma_f32_16x16x32_f16(a, b, acc0, 0, 0, 0);
      }
      float rv[4];
#pragma unroll
      for (int j = 0; j < 4; ++j) rv[j] = acc0[j] + acc1[j] + xpvA[j];

      if (t == T_ - 1) {
#pragma unroll
        for (int j = 0; j < 4; ++j)
          out[(size_t)(gA * 16 + sub * 4 + j) * 1024 + colL] = fast_tanh(rv[j]);
      } else {
        // tanh -> wave-local transpose -> tagged fire-and-forget store
#pragma unroll
        for (int j = 0; j < 4; ++j) {
          f16 hv = (f16)fast_tanh(rv[j]);
          *(f16*)(tbuf + (sub * 4 + j) * 136 + (w * 16 + lane15) * 2) = hv;
        }
        asm volatile("s_waitcnt lgkmcnt(0)" ::: "memory");
        u64 packed = *(const u64*)(tbuf + lane15 * 136 + (w * 16 + sub * 4) * 2);
        packed = (packed & ~1ull) | (u64)(((t + 1) >> 1) & 1);
        char* dst = (char*)sbuf + (size_t)((t + 1) & 1) * 131072 + baseA + stoff;
        AST64(dst, packed);
      }

      // validate B(t) tags, retry stale, commit to stB
      {
        const u32 want = (u32)((t >> 1) & 1);
        for (;;) {
          u32 bad = 0;
#pragma unroll
          for (int i = 0; i < 16; ++i) bad |= ((u32)tmp[i] ^ want) & 1u;
          if (bad == 0) break;
#pragma unroll
          for (int i = 0; i < 16; ++i) tmp[i] = ALD64(src + i * 2048);
        }
#pragma unroll
        for (int i = 0; i < 16; ++i)
          *(u64*)(stB + i * 2048 + p * 128 + q * 8) = tmp[i];
      }
      __syncthreads();
    }

    // ================= phase B: group gB, step t -> t+1 ====================
    {
      u64 tmp[16];
      const char* src = (const char*)sbuf + (size_t)((t + 1) & 1) * 131072 + baseA + p * 128 + q * 8;
      if (t < T_ - 1) {
        // issue staging loads for A(t+1) + prefetch xpvA(t+1)
#pragma unroll
        for (int i = 0; i < 16; ++i) tmp[i] = ALD64(src + i * 2048);
#pragma unroll
        for (int j = 0; j < 4; ++j)
          xpvA[j] = (float)xph[(size_t)((t + 1) * 64 + gA * 16 + sub * 4 + j) * 1024 + colL];
      }

      f32x4 acc0 = {0.f,0.f,0.f,0.f}, acc1 = {0.f,0.f,0.f,0.f};
#pragma unroll
      for (int kk = 0; kk < 32; ++kk) {
        const int s = kk * 4 + sub;
        f16x8 a = *(const f16x8*)(stBb + ((s ^ xA) << 4));
        f16x8 b = (kk < 12) ? breg[kk]
                            : *(const f16x8*)(whb + (((s ^ xB) - 48) << 4));
        if (kk & 1) acc1 = __builtin_amdgcn_mfma_f32_16x16x32_f16(a, b, acc1, 0, 0, 0);
        else        acc0 = __builtin_amdgcn_mfma_f32_16x16x32_f16(a, b, acc0, 0, 0, 0);
      }
      float rv[4];
#pragma unroll
      for (int j = 0; j < 4; ++j) rv[j] = acc0[j] + acc1[j] + xpvB[j];

      if (t == T_ - 1) {
#pragma unroll
        for (int j = 0; j < 4; ++j)
          out[(size_t)(gB * 16 + sub * 4 + j) * 1024 + colL] = fast_tanh(rv[j]);
        break;
      }
#pragma unroll
      for (int j = 0; j < 4; ++j) {
        f16 hv = (f16)fast_tanh(rv[j]);
        *(f16*)(tbuf + (sub * 4 + j) * 136 + (w * 16 + lane15) * 2) = hv;
      }
      asm volatile("s_waitcnt lgkmcnt(0)" ::: "memory");
      u64 packed = *(const u64*)(tbuf + lane15 * 136 + (w * 16 + sub * 4) * 2);
      packed = (packed & ~1ull) | (u64)(((t + 1) >> 1) & 1);
      char* dst = (char*)sbuf + (size_t)((t + 1) & 1) * 131072 + baseB + stoff;
      AST64(dst, packed);

      // validate A(t+1) tags, retry stale, commit to stA
      {
        const u32 want = (u32)(((t + 1) >> 1) & 1);
        for (;;) {
          u32 bad = 0;
#pragma unroll
          for (int i = 0; i < 16; ++i) bad |= ((u32)tmp[i] ^ want) & 1u;
          if (bad == 0) break;
#pragma unroll
          for (int i = 0; i < 16; ++i) tmp[i] = ALD64(src + i * 2048);
        }
#pragma unroll
        for (int i = 0; i < 16; ++i)
          *(u64*)(stA + i * 2048 + p * 128 + q * 8) = tmp[i];
      }
      __syncthreads();
    }
  }
}

// ---------------------------------------------------------------------------
extern "C" void kernel_launch(void* const* d_in, const int* in_sizes, int n_in,
                              void* d_out, int out_size, void* d_ws, size_t ws_size,
                              hipStream_t stream) {
  const float* x    = (const float*)d_in[0];
  const float* W    = (const float*)d_in[1];
  const float* bias = (const float*)d_in[2];
  float* out = (float*)d_out;
  char* w = (char*)d_ws;

  f16* xph = (f16*)(w + XPH_OFF);
  f16* WxT = (f16*)(w + WXT_OFF);
  f16* WhT = (f16*)(w + WHT_OFF);
  f16* sbuf = (f16*)(w + SBUF_OFF);

  // tag-aware image init: parity 0 = state0 (tag 0), parity 1 = tag 1
  k_init<<<dim3(128), dim3(256), 0, stream>>>((u64*)(w + SBUF_OFF));

  k_prep<<<dim3(48 * 32), dim3(256), 0, stream>>>(W, WxT, WhT);
  k_xproj<<<dim3(512), dim3(256), 0, stream>>>(x, WxT, bias, xph);
  k_rnn<<<dim3(32), dim3(256), 0, stream>>>(xph, WhT, sbuf, out);
}